// Round 4
// baseline (172.949 us; speedup 1.0000x reference)
//
#include <hip/hip_runtime.h>
#include <cstddef>

typedef short short8 __attribute__((ext_vector_type(8)));
typedef unsigned short ushort8 __attribute__((ext_vector_type(8)));
typedef float f32x4 __attribute__((ext_vector_type(4)));

#define AS1(p) ((const __attribute__((address_space(1))) void*)(p))
#define AS3(p) ((__attribute__((address_space(3))) void*)(p))

__device__ __forceinline__ unsigned short f2bf(float f) {
  unsigned int u = __builtin_bit_cast(unsigned int, f);
  u += 0x7FFFu + ((u >> 16) & 1u);   // round-to-nearest-even
  return (unsigned short)(u >> 16);
}

__device__ __forceinline__ void gload_lds16(const void* g, void* l) {
  __builtin_amdgcn_global_load_lds(AS1(g), AS3(l), 16, 0, 0);
}

template <int N>
__device__ __forceinline__ void vwait() {
  asm volatile("s_waitcnt vmcnt(%0)" :: "n"(N) : "memory");
}

// ---------------------------------------------------------------------------
// fp32 -> bf16 elementwise convert
// ---------------------------------------------------------------------------
__global__ void cvt_f32_bf16(const float* __restrict__ in,
                             unsigned short* __restrict__ out, int n4) {
  int i = blockIdx.x * blockDim.x + threadIdx.x;
  if (i >= n4) return;
  float4 v = *reinterpret_cast<const float4*>(in + (size_t)i * 4);
  ushort4 o;
  o.x = f2bf(v.x); o.y = f2bf(v.y); o.z = f2bf(v.z); o.w = f2bf(v.w);
  *reinterpret_cast<ushort4*>(out + (size_t)i * 4) = o;
}

// ---------------------------------------------------------------------------
// fp32 [Kd][Nd] -> bf16 [Nd][Kd] tiled transpose+convert, block (32,8)
// ---------------------------------------------------------------------------
__global__ void transpose_cvt(const float* __restrict__ in,
                              unsigned short* __restrict__ out,
                              int Kd, int Nd) {
  __shared__ float tile[32][33];
  const int n0 = blockIdx.x * 32;
  const int k0 = blockIdx.y * 32;
  const int tx = threadIdx.x;
  const int ty = threadIdx.y;
#pragma unroll
  for (int i = 0; i < 4; ++i)
    tile[ty + i * 8][tx] = in[(size_t)(k0 + ty + i * 8) * Nd + n0 + tx];
  __syncthreads();
#pragma unroll
  for (int i = 0; i < 4; ++i)
    out[(size_t)(n0 + ty + i * 8) * Kd + k0 + tx] = f2bf(tile[tx][ty + i * 8]);
}

// ---------------------------------------------------------------------------
// Ring-pipelined GEMM: C[M][N] = A[M][K]*B'[N][K] (+bias, opt relu->bf16)
// BM=256, BK=32, 4-deep LDS ring (slot = 16KB A + BN*64B B), 8 waves WMxWN.
// Stage tile t+3 during tile t (lead 4-6 phases); end-of-tile vmcnt(2*UNITS)
// guarantees tile t+1 (in-order vmcnt retirement) while keeping t+2/t+3 in
// flight; ONE barrier per K-tile. LDS swizzle: a ^= (((r&3)^((r>>2)&3))<<4),
// applied to pre-swizzled global stage source AND ds_read (rule #21).
// ---------------------------------------------------------------------------
#define TILE_BODY(T, DO_STAGE, STAGE_T)                                        \
  {                                                                            \
    char* s = lds + (size_t)((T) & 3) * SLOT;                                  \
    _Pragma("unroll")                                                          \
    for (int h = 0; h < NPH; ++h) {                                            \
      if (h == 0) {                                                            \
        _Pragma("unroll")                                                      \
        for (int ni = 0; ni < 4; ++ni)                                         \
          bfr[ni] = *reinterpret_cast<const short8*>(s + brd[ni]);             \
      }                                                                        \
      short8 afr[4];                                                           \
      _Pragma("unroll")                                                        \
      for (int m2 = 0; m2 < 4; ++m2)                                           \
        afr[m2] = *reinterpret_cast<const short8*>(s + ard[h * 4 + m2]);       \
      if (h == 0 && (DO_STAGE)) stage(STAGE_T);                                \
      asm volatile("s_waitcnt lgkmcnt(0)" ::: "memory");                       \
      __builtin_amdgcn_sched_barrier(0);                                       \
      __builtin_amdgcn_s_setprio(1);                                           \
      _Pragma("unroll")                                                        \
      for (int m2 = 0; m2 < 4; ++m2) {                                         \
        _Pragma("unroll")                                                      \
        for (int ni = 0; ni < 4; ++ni)                                         \
          acc[h * 4 + m2][ni] = __builtin_amdgcn_mfma_f32_16x16x32_bf16(       \
              afr[m2], bfr[ni], acc[h * 4 + m2][ni], 0, 0, 0);                 \
      }                                                                        \
      __builtin_amdgcn_s_setprio(0);                                           \
    }                                                                          \
  }

#define TILE_END(WN_)                                                          \
  vwait<WN_>();                                                                \
  __builtin_amdgcn_s_barrier();                                                \
  __builtin_amdgcn_sched_barrier(0);

template <int WM, int BN, int RELU_BF16_OUT>
__global__ __launch_bounds__(512, 2)
void gemm_ring(const unsigned short* __restrict__ A, int lda,
               const unsigned short* __restrict__ B, int ldb,
               const float* __restrict__ bias,
               void* __restrict__ C, int ldc, int K, int nbx) {
  constexpr int WN     = 8 / WM;          // waves: WM x WN
  constexpr int MB     = 256 / WM / 16;   // A frags per wave (8 or 4)
  constexpr int NPH    = MB / 4;          // phases per K-tile (2 or 1)
  constexpr int BUNITS = BN / 128;        // B stage units (8KB each)
  constexpr int UNITS  = 2 + BUNITS;      // loads/thread per K-tile
  constexpr int SLOT   = 16384 + BN * 64; // ring slot bytes
  extern __shared__ char lds[];

  const int tid  = threadIdx.x;
  const int lane = tid & 63;
  const int wid  = tid >> 6;
  const int wm   = wid / WN;
  const int wn   = wid % WN;

  // XCD-chunked swizzle (grid % 8 == 0)
  const int cpx     = gridDim.x >> 3;
  const int logical = (blockIdx.x & 7) * cpx + (blockIdx.x >> 3);
  const int bx = logical % nbx;
  const int by = logical / nbx;
  const int m0 = by * 256;
  const int n0 = bx * BN;

  f32x4 acc[MB][4];
#pragma unroll
  for (int i = 0; i < MB; ++i)
#pragma unroll
    for (int j = 0; j < 4; ++j)
      acc[i][j] = (f32x4){0.f, 0.f, 0.f, 0.f};

  // --- stage map: linear LDS dest, pre-swizzled global source --------------
  const int p    = tid * 16;                       // within-unit byte
  const int r    = p >> 6;                         // unit row 0..127
  const int smsk = (((r & 3) ^ ((r >> 2) & 3)) << 4);
  const int kel0 = (((p & 63) ^ smsk) >> 1);       // k element 0..24
  size_t aofs0 = (size_t)(m0 + r) * lda + kel0;
  size_t aofs1 = (size_t)(m0 + 128 + r) * lda + kel0;
  size_t bofs0 = (size_t)(n0 + r) * ldb + kel0;
  size_t bofs1 = (BUNITS == 2) ? (size_t)(n0 + 128 + r) * ldb + kel0 : 0;
  const int ldst = (tid >> 6) * 1024;              // wave-uniform base

  auto stage = [&](int t) {   // tile t -> slot t&3; UNITS loads/thread
    char* s = lds + (size_t)(t & 3) * SLOT;
    const int kk = t * 32;
    gload_lds16(A + aofs0 + kk, s + ldst);
    gload_lds16(A + aofs1 + kk, s + 8192 + ldst);
    gload_lds16(B + bofs0 + kk, s + 16384 + ldst);
    if constexpr (BUNITS == 2)
      gload_lds16(B + bofs1 + kk, s + 24576 + ldst);
  };

  // --- swizzled ds_read fragment offsets -----------------------------------
  int ard[MB], brd[4];
#pragma unroll
  for (int mi = 0; mi < MB; ++mi) {
    int nat = (wm * (MB * 16) + mi * 16 + (lane & 15)) * 64 + (lane >> 4) * 16;
    int rr  = nat >> 6;
    ard[mi] = nat ^ ((((rr & 3) ^ ((rr >> 2) & 3))) << 4);
  }
#pragma unroll
  for (int ni = 0; ni < 4; ++ni) {
    int nat = (wn * 64 + ni * 16 + (lane & 15)) * 64 + (lane >> 4) * 16;
    int rr  = nat >> 6;
    brd[ni] = 16384 + (nat ^ ((((rr & 3) ^ ((rr >> 2) & 3))) << 4));
  }

  // --- prologue: stage tiles 0,1,2; wait tile0 (leave 1,2 in flight) -------
  stage(0); stage(1); stage(2);
  TILE_END(2 * UNITS);

  const int NT = K >> 5;
  short8 bfr[4];
  for (int t = 0; t < NT - 3; ++t) {
    TILE_BODY(t, true, t + 3);
    TILE_END(2 * UNITS);       // tile t+1 guaranteed; t+2,t+3 stay in flight
  }
  TILE_BODY(NT - 3, false, 0);
  TILE_END(UNITS);             // tile NT-2 guaranteed; NT-1 in flight
  TILE_BODY(NT - 2, false, 0);
  TILE_END(0);                 // tile NT-1 guaranteed
  TILE_BODY(NT - 1, false, 0);

  // --- epilogue: D row=(lane>>4)*4+reg, col=lane&15 (m89-verified) ---------
  const int row0 = m0 + wm * (MB * 16) + (lane >> 4) * 4;
  const int col0 = n0 + wn * 64 + (lane & 15);
#pragma unroll
  for (int ni = 0; ni < 4; ++ni) {
    const int c = col0 + ni * 16;
    const float bv = bias[c];
#pragma unroll
    for (int mi = 0; mi < MB; ++mi) {
#pragma unroll
      for (int rr = 0; rr < 4; ++rr) {
        const size_t idx = (size_t)(row0 + mi * 16 + rr) * ldc + c;
        float v = acc[mi][ni][rr] + bv;
        if (RELU_BF16_OUT) {
          v = v > 0.f ? v : 0.f;
          ((unsigned short*)C)[idx] = f2bf(v);
        } else {
          ((float*)C)[idx] = v;
        }
      }
    }
  }
}

// ---------------------------------------------------------------------------
// Fallback 128^2 GEMM (round-2, verified) for small-ws configurations.
// ---------------------------------------------------------------------------
template <int A_F32, int RELU_BF16_OUT>
__global__ __launch_bounds__(256, 2)
void gemm_bf16(const void* __restrict__ Ap, int lda,
               const unsigned short* __restrict__ B, int ldb,
               const float* __restrict__ bias,
               void* __restrict__ C, int ldc,
               int K, int beta) {
  __shared__ char lds[32768];
  char* const As = lds;
  char* const Bs = lds + 16384;

  const int tid  = threadIdx.x;
  const int lane = tid & 63;
  const int w    = tid >> 6;
  const int wm   = w >> 1;
  const int wn   = w & 1;
  const int m0   = blockIdx.y * 128;
  const int n0   = blockIdx.x * 128;

  f32x4 acc[4][4];
#pragma unroll
  for (int i = 0; i < 4; ++i)
#pragma unroll
    for (int j = 0; j < 4; ++j)
      acc[i][j] = (f32x4){0.f, 0.f, 0.f, 0.f};

  int srow[4], scol[4], sbase[4];
#pragma unroll
  for (int j = 0; j < 4; ++j) {
    const int stored  = (j * 256 + tid) * 16;
    const int natural = stored ^ (((stored >> 7) & 7) << 4);
    srow[j]  = natural >> 7;
    scol[j]  = (natural & 127) >> 1;
    sbase[j] = (j * 256 + (tid & 192)) * 16;
  }

  size_t agofs[4];
  int ast[4];
  if (A_F32) {
#pragma unroll
    for (int pq = 0; pq < 4; ++pq) {
      const int idx = pq * 256 + tid;
      const int rr  = idx >> 3;
      const int kbe = (idx & 7) * 8;
      agofs[pq] = (size_t)(m0 + rr) * lda + kbe;
      const int nat = rr * 128 + kbe * 2;
      ast[pq] = nat ^ (((nat >> 7) & 7) << 4);
    }
  }

  const int nsteps = K >> 6;
  for (int ks = 0; ks < nsteps; ++ks) {
    const int k0 = ks << 6;
    if (A_F32) {
      const float* Af = (const float*)Ap;
#pragma unroll
      for (int pq = 0; pq < 4; ++pq) {
        const float* sp = Af + agofs[pq] + k0;
        float4 x0 = *reinterpret_cast<const float4*>(sp);
        float4 x1 = *reinterpret_cast<const float4*>(sp + 4);
        ushort8 v;
        v[0] = f2bf(x0.x); v[1] = f2bf(x0.y); v[2] = f2bf(x0.z); v[3] = f2bf(x0.w);
        v[4] = f2bf(x1.x); v[5] = f2bf(x1.y); v[6] = f2bf(x1.z); v[7] = f2bf(x1.w);
        *reinterpret_cast<ushort8*>(As + ast[pq]) = v;
      }
    } else {
      const unsigned short* Ab = (const unsigned short*)Ap;
#pragma unroll
      for (int j = 0; j < 4; ++j)
        gload_lds16(Ab + (size_t)(m0 + srow[j]) * lda + (k0 + scol[j]),
                    As + sbase[j]);
    }
#pragma unroll
    for (int j = 0; j < 4; ++j)
      gload_lds16(B + (size_t)(n0 + srow[j]) * ldb + (k0 + scol[j]),
                  Bs + sbase[j]);
    __syncthreads();

#pragma unroll
    for (int kk = 0; kk < 2; ++kk) {
      const int kb = kk * 64 + (lane >> 4) * 16;
      short8 af[4], bfv[4];
#pragma unroll
      for (int mi = 0; mi < 4; ++mi) {
        int nat = (wm * 64 + mi * 16 + (lane & 15)) * 128 + kb;
        int st  = nat ^ (((nat >> 7) & 7) << 4);
        af[mi] = *reinterpret_cast<const short8*>(As + st);
      }
#pragma unroll
      for (int ni = 0; ni < 4; ++ni) {
        int nat = (wn * 64 + ni * 16 + (lane & 15)) * 128 + kb;
        int st  = nat ^ (((nat >> 7) & 7) << 4);
        bfv[ni] = *reinterpret_cast<const short8*>(Bs + st);
      }
#pragma unroll
      for (int mi = 0; mi < 4; ++mi)
#pragma unroll
        for (int ni = 0; ni < 4; ++ni)
          acc[mi][ni] = __builtin_amdgcn_mfma_f32_16x16x32_bf16(
              af[mi], bfv[ni], acc[mi][ni], 0, 0, 0);
    }
    __syncthreads();
  }

  const int row0 = m0 + wm * 64 + (lane >> 4) * 4;
  const int col0 = n0 + wn * 64 + (lane & 15);
#pragma unroll
  for (int ni = 0; ni < 4; ++ni) {
    const int c = col0 + ni * 16;
    const float bv = beta ? 0.f : bias[c];
#pragma unroll
    for (int mi = 0; mi < 4; ++mi) {
#pragma unroll
      for (int rr = 0; rr < 4; ++rr) {
        const size_t idx = (size_t)(row0 + mi * 16 + rr) * ldc + c;
        float v = acc[mi][ni][rr] + bv;
        if (RELU_BF16_OUT) {
          v = v > 0.f ? v : 0.f;
          ((unsigned short*)C)[idx] = f2bf(v);
        } else {
          if (beta) v += ((float*)C)[idx];
          ((float*)C)[idx] = v;
        }
      }
    }
  }
}

// ---------------------------------------------------------------------------
extern "C" void kernel_launch(void* const* d_in, const int* in_sizes, int n_in,
                              void* d_out, int out_size, void* d_ws, size_t ws_size,
                              hipStream_t stream) {
  const float* X  = (const float*)d_in[0];  // [8192][1024]
  const float* W1 = (const float*)d_in[1];  // [1024][4096]
  const float* b1 = (const float*)d_in[2];  // [4096]
  const float* W2 = (const float*)d_in[3];  // [4096][1024]
  const float* b2 = (const float*)d_in[4];  // [1024]
  float* out = (float*)d_out;               // [8192][1024] f32

  const int M = 8192, H = 1024, I = 4096;
  const size_t MB = 1024 * 1024;

  char* ws = (char*)d_ws;
  unsigned short* W1t = (unsigned short*)ws;            // [I][H] bf16, 8 MB
  unsigned short* W2t = (unsigned short*)(ws + 8 * MB); // [H][I] bf16, 8 MB

  transpose_cvt<<<dim3(I / 32, H / 32), dim3(32, 8), 0, stream>>>(W1, W1t, H, I);
  transpose_cvt<<<dim3(H / 32, I / 32), dim3(32, 8), 0, stream>>>(W2, W2t, I, H);

  if (ws_size >= 80 * MB) {
    // Fast path: ring-pipelined 256-row GEMMs. Xbf parked in d_out tail
    // (fully consumed by L1 before the single L2 dispatch writes d_out).
    unsigned short* Xbf = (unsigned short*)((char*)d_out + 16 * MB);
    unsigned short* Hbf = (unsigned short*)(ws + 16 * MB);   // [M][I] bf16
    int n4 = (M * H) / 4;
    cvt_f32_bf16<<<(n4 + 255) / 256, 256, 0, stream>>>(X, Xbf, n4);
    // L1: Hbf = relu(X*W1+b1). BM=256,BN=256, grid 16x32=512, LDS 128 KiB.
    gemm_ring<2, 256, 1><<<512, 512, 131072, stream>>>(
        Xbf, H, W1t, H, b1, Hbf, I, H, I / 256);
    // L2: out = Hbf*W2+b2. BM=256,BN=128, grid 8x32=256, LDS 96 KiB.
    gemm_ring<4, 128, 0><<<256, 512, 98304, stream>>>(
        Hbf, I, W2t, I, b2, out, H, I, H / 128);
    return;
  }

  // Fallback: round-2 adaptive chunked path (verified).
  int Ic, useXbf;
  unsigned short* Xbf = nullptr;
  unsigned short* Hc;
  if (ws_size >= 64 * MB) {
    Ic = 2048; useXbf = 1;
    Xbf = (unsigned short*)(ws + 16 * MB);
    Hc  = (unsigned short*)(ws + 32 * MB);
  } else if (ws_size >= 48 * MB) {
    Ic = 1024; useXbf = 1;
    Xbf = (unsigned short*)(ws + 16 * MB);
    Hc  = (unsigned short*)(ws + 32 * MB);
  } else if (ws_size >= 32 * MB) {
    Ic = 1024; useXbf = 0;
    Hc  = (unsigned short*)(ws + 16 * MB);
  } else if (ws_size >= 24 * MB) {
    Ic = 512;  useXbf = 0;
    Hc  = (unsigned short*)(ws + 16 * MB);
  } else if (ws_size >= 20 * MB) {
    Ic = 256;  useXbf = 0;
    Hc  = (unsigned short*)(ws + 16 * MB);
  } else {
    Ic = 128;  useXbf = 0;
    Hc  = (unsigned short*)(ws + 16 * MB);
  }

  if (useXbf) {
    int n4 = (M * H) / 4;
    cvt_f32_bf16<<<(n4 + 255) / 256, 256, 0, stream>>>(X, Xbf, n4);
  }

  const int nch = I / Ic;
  for (int c = 0; c < nch; ++c) {
    const int i0 = c * Ic;
    if (useXbf)
      gemm_bf16<0, 1><<<dim3(Ic / 128, M / 128), 256, 0, stream>>>(
          Xbf, H, W1t + (size_t)i0 * H, H, b1 + i0, Hc, Ic, H, 0);
    else
      gemm_bf16<1, 1><<<dim3(Ic / 128, M / 128), 256, 0, stream>>>(
          X, H, W1t + (size_t)i0 * H, H, b1 + i0, Hc, Ic, H, 0);
    gemm_bf16<0, 0><<<dim3(H / 128, M / 128), 256, 0, stream>>>(
        Hc, Ic, W2t + i0, I, b2, out, H, Ic, c > 0);
  }
}

// Round 5
// 169.000 us; speedup vs baseline: 1.0234x; 1.0234x over previous
//
#include <hip/hip_runtime.h>
#include <cstddef>

typedef short short8 __attribute__((ext_vector_type(8)));
typedef unsigned short ushort8 __attribute__((ext_vector_type(8)));
typedef float f32x4 __attribute__((ext_vector_type(4)));

#define AS1(p) ((const __attribute__((address_space(1))) void*)(p))
#define AS3(p) ((__attribute__((address_space(3))) void*)(p))

__device__ __forceinline__ unsigned short f2bf(float f) {
  unsigned int u = __builtin_bit_cast(unsigned int, f);
  u += 0x7FFFu + ((u >> 16) & 1u);   // round-to-nearest-even
  return (unsigned short)(u >> 16);
}

__device__ __forceinline__ void gload_lds16(const void* g, void* l) {
  __builtin_amdgcn_global_load_lds(AS1(g), AS3(l), 16, 0, 0);
}

template <int N>
__device__ __forceinline__ void vwait() {
  asm volatile("s_waitcnt vmcnt(%0)" :: "n"(N) : "memory");
}

// ---------------------------------------------------------------------------
// fp32 -> bf16 elementwise convert
// ---------------------------------------------------------------------------
__global__ void cvt_f32_bf16(const float* __restrict__ in,
                             unsigned short* __restrict__ out, int n4) {
  int i = blockIdx.x * blockDim.x + threadIdx.x;
  if (i >= n4) return;
  float4 v = *reinterpret_cast<const float4*>(in + (size_t)i * 4);
  ushort4 o;
  o.x = f2bf(v.x); o.y = f2bf(v.y); o.z = f2bf(v.z); o.w = f2bf(v.w);
  *reinterpret_cast<ushort4*>(out + (size_t)i * 4) = o;
}

// ---------------------------------------------------------------------------
// fp32 [Kd][Nd] -> bf16 [Nd][Kd] tiled transpose+convert, block (32,8)
// ---------------------------------------------------------------------------
__global__ void transpose_cvt(const float* __restrict__ in,
                              unsigned short* __restrict__ out,
                              int Kd, int Nd) {
  __shared__ float tile[32][33];
  const int n0 = blockIdx.x * 32;
  const int k0 = blockIdx.y * 32;
  const int tx = threadIdx.x;
  const int ty = threadIdx.y;
#pragma unroll
  for (int i = 0; i < 4; ++i)
    tile[ty + i * 8][tx] = in[(size_t)(k0 + ty + i * 8) * Nd + n0 + tx];
  __syncthreads();
#pragma unroll
  for (int i = 0; i < 4; ++i)
    out[(size_t)(n0 + ty + i * 8) * Kd + k0 + tx] = f2bf(tile[tx][ty + i * 8]);
}

// ---------------------------------------------------------------------------
// K-half 8-phase GEMM: C[M][N] = A[M][K]*B'[N][K] (+bias, opt relu->bf16)
// BM=256, BK=64 split into two 32-k HALVES, double-buffered per half:
//   A[2 dbuf][2 kh] (16KB each) + B[2][2] (BN*64 B each).
// Half layout: 256 (or BN) rows x 32k stored as 128-byte LINES pairing rows
// (r, r+NR/2); swizzle a^=((a>>7)&7)<<4 on stage-source + ds_read (both
// sides, rule #21) -> byte-identical to the round-2 measured-0-conflict
// pattern. Phase (kk,mh): one half frees per phase; stage stream
//   P1:Ak1(O) P2:Bk0(E') P3:Ak0(E') P4:Bk1(E') P5:Ak1(E')
//   P6:Bk0(O') P7:Ak0(O') P8:Bk1(O')
// waits vmcnt(2+2*BL) at P4/P8 drain exactly the next tile's 4 halves
// (load-count bookkeeping verified incl. prologue + tail).
// ---------------------------------------------------------------------------
#define PHASE(D, KK, MH, STAGE, WAIT)                                          \
  {                                                                            \
    char* ab = lds + (D) * 32768 + (KK) * 16384;                               \
    if ((MH) == 0) {                                                           \
      char* bb = lds + 65536 + (D) * 2 * BKH + (KK) * BKH;                     \
      _Pragma("unroll")                                                        \
      for (int ni = 0; ni < NB; ++ni)                                          \
        bfr[ni] = *reinterpret_cast<const short8*>(bb + brd[ni]);              \
    }                                                                          \
    short8 afr[4];                                                             \
    _Pragma("unroll")                                                          \
    for (int m2 = 0; m2 < 4; ++m2)                                             \
      afr[m2] = *reinterpret_cast<const short8*>(ab + ard[(MH) * 4 + m2]);     \
    STAGE;                                                                     \
    __builtin_amdgcn_sched_barrier(0);                                         \
    __builtin_amdgcn_s_barrier();                                              \
    asm volatile("s_waitcnt lgkmcnt(0)" ::: "memory");                         \
    __builtin_amdgcn_sched_barrier(0);                                         \
    __builtin_amdgcn_s_setprio(1);                                             \
    _Pragma("unroll")                                                          \
    for (int m2 = 0; m2 < 4; ++m2) {                                           \
      _Pragma("unroll")                                                        \
      for (int ni = 0; ni < NB; ++ni)                                          \
        acc[(MH) * 4 + m2][ni] = __builtin_amdgcn_mfma_f32_16x16x32_bf16(      \
            afr[m2], bfr[ni], acc[(MH) * 4 + m2][ni], 0, 0, 0);                \
    }                                                                          \
    __builtin_amdgcn_s_setprio(0);                                             \
    WAIT;                                                                      \
    __builtin_amdgcn_s_barrier();                                              \
  }

template <int BN, int RELU_BF16_OUT>
__global__ __launch_bounds__(512, 2)
void gemm_kh(const unsigned short* __restrict__ A, int lda,
             const unsigned short* __restrict__ B, int ldb,
             const float* __restrict__ bias,
             void* __restrict__ C, int ldc, int K, int nbx) {
  constexpr int NB      = BN / 64;        // B frags per wave (4 or 2)
  constexpr int PWN     = BN / 4;         // per-wave N (64 or 32)
  constexpr int BKH     = BN * 64;        // bytes per B k-half (16K or 8K)
  constexpr int BL      = BN / 128;       // loads per B-half stage (2 or 1)
  constexpr int WSTEADY = 2 + 2 * BL;     // leave = P2+P3+P4 stages
  constexpr int NSH     = (BN == 256) ? 7 : 6;  // log2(NR/2) for B rows
  extern __shared__ char lds[];

  const int tid  = threadIdx.x;
  const int lane = tid & 63;
  const int wid  = tid >> 6;
  const int wm   = wid >> 2;   // 0..1  (row half)
  const int wn   = wid & 3;    // 0..3  (col quarter)

  // XCD-chunked swizzle (grid % 8 == 0)
  const int cpx     = gridDim.x >> 3;
  const int logical = (blockIdx.x & 7) * cpx + (blockIdx.x >> 3);
  const int bx = logical % nbx;
  const int by = logical / nbx;
  const int m0 = by * 256;
  const int n0 = bx * BN;

  f32x4 acc[8][NB];
#pragma unroll
  for (int i = 0; i < 8; ++i)
#pragma unroll
    for (int j = 0; j < NB; ++j)
      acc[i][j] = (f32x4){0.f, 0.f, 0.f, 0.f};

  // --- stage maps: linear LDS dest, pre-swizzled global source -------------
  size_t aG[2];
  size_t bG[2];
#pragma unroll
  for (int u = 0; u < 2; ++u) {
    const int s    = (u * 512 + tid) * 16;
    const int nat  = s ^ (((s >> 7) & 7) << 4);
    const int line = nat >> 7;
    const int boff = nat & 127;
    const int sub  = (boff >> 6) & 1;
    const int kel  = (boff & 63) >> 1;
    aG[u] = (size_t)(m0 + sub * 128 + line) * lda + kel;
    if (u < BL) {
      const int brow = sub * (BN / 2) + line;
      bG[u] = (size_t)(n0 + brow) * ldb + kel;
    } else {
      bG[u] = 0;
    }
  }
  const int wbase = wid * 1024;   // wave-uniform LDS base (+lane*16 by HW)

  auto stage_a = [&](int d, int kk, int t) {
    char* dst = lds + d * 32768 + kk * 16384;
    const size_t kofs = (size_t)t * 64 + kk * 32;
    gload_lds16(A + aG[0] + kofs, dst + wbase);
    gload_lds16(A + aG[1] + kofs, dst + 8192 + wbase);
  };
  auto stage_b = [&](int d, int kk, int t) {
    char* dst = lds + 65536 + d * 2 * BKH + kk * BKH;
    const size_t kofs = (size_t)t * 64 + kk * 32;
    gload_lds16(B + bG[0] + kofs, dst + wbase);
    if constexpr (BL == 2)
      gload_lds16(B + bG[1] + kofs, dst + 8192 + wbase);
  };

  // --- swizzled ds_read fragment offsets (within one k-half buffer) --------
  int ard[8], brd[NB];
#pragma unroll
  for (int mi = 0; mi < 8; ++mi) {
    const int row  = wm * 128 + mi * 16 + (lane & 15);
    const int nat  = (row & 127) * 128 + (row >> 7) * 64 + (lane >> 4) * 16;
    ard[mi] = nat ^ (((nat >> 7) & 7) << 4);
  }
#pragma unroll
  for (int ni = 0; ni < NB; ++ni) {
    const int row  = wn * PWN + ni * 16 + (lane & 15);
    const int nat  = (row & ((BN / 2) - 1)) * 128 + (row >> NSH) * 64 +
                     (lane >> 4) * 16;
    brd[ni] = nat ^ (((nat >> 7) & 7) << 4);
  }

  // --- prologue: E0 all 4 halves + O0 first 3; wait E0 complete ------------
  stage_b(0, 0, 0); stage_a(0, 0, 0); stage_b(0, 1, 0); stage_a(0, 1, 0);
  stage_b(1, 0, 1); stage_a(1, 0, 1); stage_b(1, 1, 1);
  vwait<WSTEADY>();
  __builtin_amdgcn_s_barrier();

  const int ni_ = (K >> 7);   // iterations of 2 K-tiles
  short8 bfr[NB];
  for (int it = 0; it < ni_ - 1; ++it) {
    const int t = it << 1;
    PHASE(0, 0, 0, stage_a(1, 1, t + 1), );
    PHASE(0, 0, 1, stage_b(0, 0, t + 2), );
    PHASE(0, 1, 0, stage_a(0, 0, t + 2), );
    PHASE(0, 1, 1, stage_b(0, 1, t + 2), vwait<WSTEADY>());
    PHASE(1, 0, 0, stage_a(0, 1, t + 2), );
    PHASE(1, 0, 1, stage_b(1, 0, t + 3), );
    PHASE(1, 1, 0, stage_a(1, 0, t + 3), );
    PHASE(1, 1, 1, stage_b(1, 1, t + 3), vwait<WSTEADY>());
  }
  {
    const int tl = (ni_ << 1) - 1;   // last odd tile index
    PHASE(0, 0, 0, stage_a(1, 1, tl), );
    PHASE(0, 0, 1, , );
    PHASE(0, 1, 0, , );
    PHASE(0, 1, 1, , vwait<0>());
    PHASE(1, 0, 0, , );
    PHASE(1, 0, 1, , );
    PHASE(1, 1, 0, , );
    PHASE(1, 1, 1, , );
  }

  // --- epilogue: D row=(lane>>4)*4+reg, col=lane&15 (m89-verified) ---------
  const int row0 = m0 + wm * 128 + (lane >> 4) * 4;
  const int col0 = n0 + wn * PWN + (lane & 15);
#pragma unroll
  for (int ni = 0; ni < NB; ++ni) {
    const int c = col0 + ni * 16;
    const float bv = bias[c];
#pragma unroll
    for (int mi = 0; mi < 8; ++mi) {
#pragma unroll
      for (int r = 0; r < 4; ++r) {
        const size_t idx = (size_t)(row0 + mi * 16 + r) * ldc + c;
        float v = acc[mi][ni][r] + bv;
        if (RELU_BF16_OUT) {
          v = v > 0.f ? v : 0.f;
          ((unsigned short*)C)[idx] = f2bf(v);
        } else {
          ((float*)C)[idx] = v;
        }
      }
    }
  }
}

// ---------------------------------------------------------------------------
// Fallback 128^2 GEMM (round-2, verified) for small-ws configurations.
// ---------------------------------------------------------------------------
template <int A_F32, int RELU_BF16_OUT>
__global__ __launch_bounds__(256, 2)
void gemm_bf16(const void* __restrict__ Ap, int lda,
               const unsigned short* __restrict__ B, int ldb,
               const float* __restrict__ bias,
               void* __restrict__ C, int ldc,
               int K, int beta) {
  __shared__ char lds[32768];
  char* const As = lds;
  char* const Bs = lds + 16384;

  const int tid  = threadIdx.x;
  const int lane = tid & 63;
  const int w    = tid >> 6;
  const int wm   = w >> 1;
  const int wn   = w & 1;
  const int m0   = blockIdx.y * 128;
  const int n0   = blockIdx.x * 128;

  f32x4 acc[4][4];
#pragma unroll
  for (int i = 0; i < 4; ++i)
#pragma unroll
    for (int j = 0; j < 4; ++j)
      acc[i][j] = (f32x4){0.f, 0.f, 0.f, 0.f};

  int srow[4], scol[4], sbase[4];
#pragma unroll
  for (int j = 0; j < 4; ++j) {
    const int stored  = (j * 256 + tid) * 16;
    const int natural = stored ^ (((stored >> 7) & 7) << 4);
    srow[j]  = natural >> 7;
    scol[j]  = (natural & 127) >> 1;
    sbase[j] = (j * 256 + (tid & 192)) * 16;
  }

  size_t agofs[4];
  int ast[4];
  if (A_F32) {
#pragma unroll
    for (int pq = 0; pq < 4; ++pq) {
      const int idx = pq * 256 + tid;
      const int rr  = idx >> 3;
      const int kbe = (idx & 7) * 8;
      agofs[pq] = (size_t)(m0 + rr) * lda + kbe;
      const int nat = rr * 128 + kbe * 2;
      ast[pq] = nat ^ (((nat >> 7) & 7) << 4);
    }
  }

  const int nsteps = K >> 6;
  for (int ks = 0; ks < nsteps; ++ks) {
    const int k0 = ks << 6;
    if (A_F32) {
      const float* Af = (const float*)Ap;
#pragma unroll
      for (int pq = 0; pq < 4; ++pq) {
        const float* sp = Af + agofs[pq] + k0;
        float4 x0 = *reinterpret_cast<const float4*>(sp);
        float4 x1 = *reinterpret_cast<const float4*>(sp + 4);
        ushort8 v;
        v[0] = f2bf(x0.x); v[1] = f2bf(x0.y); v[2] = f2bf(x0.z); v[3] = f2bf(x0.w);
        v[4] = f2bf(x1.x); v[5] = f2bf(x1.y); v[6] = f2bf(x1.z); v[7] = f2bf(x1.w);
        *reinterpret_cast<ushort8*>(As + ast[pq]) = v;
      }
    } else {
      const unsigned short* Ab = (const unsigned short*)Ap;
#pragma unroll
      for (int j = 0; j < 4; ++j)
        gload_lds16(Ab + (size_t)(m0 + srow[j]) * lda + (k0 + scol[j]),
                    As + sbase[j]);
    }
#pragma unroll
    for (int j = 0; j < 4; ++j)
      gload_lds16(B + (size_t)(n0 + srow[j]) * ldb + (k0 + scol[j]),
                  Bs + sbase[j]);
    __syncthreads();

#pragma unroll
    for (int kk = 0; kk < 2; ++kk) {
      const int kb = kk * 64 + (lane >> 4) * 16;
      short8 af[4], bfv[4];
#pragma unroll
      for (int mi = 0; mi < 4; ++mi) {
        int nat = (wm * 64 + mi * 16 + (lane & 15)) * 128 + kb;
        int st  = nat ^ (((nat >> 7) & 7) << 4);
        af[mi] = *reinterpret_cast<const short8*>(As + st);
      }
#pragma unroll
      for (int ni = 0; ni < 4; ++ni) {
        int nat = (wn * 64 + ni * 16 + (lane & 15)) * 128 + kb;
        int st  = nat ^ (((nat >> 7) & 7) << 4);
        bfv[ni] = *reinterpret_cast<const short8*>(Bs + st);
      }
#pragma unroll
      for (int mi = 0; mi < 4; ++mi)
#pragma unroll
        for (int ni = 0; ni < 4; ++ni)
          acc[mi][ni] = __builtin_amdgcn_mfma_f32_16x16x32_bf16(
              af[mi], bfv[ni], acc[mi][ni], 0, 0, 0);
    }
    __syncthreads();
  }

  const int row0 = m0 + wm * 64 + (lane >> 4) * 4;
  const int col0 = n0 + wn * 64 + (lane & 15);
#pragma unroll
  for (int ni = 0; ni < 4; ++ni) {
    const int c = col0 + ni * 16;
    const float bv = beta ? 0.f : bias[c];
#pragma unroll
    for (int mi = 0; mi < 4; ++mi) {
#pragma unroll
      for (int rr = 0; rr < 4; ++rr) {
        const size_t idx = (size_t)(row0 + mi * 16 + rr) * ldc + c;
        float v = acc[mi][ni][rr] + bv;
        if (RELU_BF16_OUT) {
          v = v > 0.f ? v : 0.f;
          ((unsigned short*)C)[idx] = f2bf(v);
        } else {
          if (beta) v += ((float*)C)[idx];
          ((float*)C)[idx] = v;
        }
      }
    }
  }
}

// ---------------------------------------------------------------------------
extern "C" void kernel_launch(void* const* d_in, const int* in_sizes, int n_in,
                              void* d_out, int out_size, void* d_ws, size_t ws_size,
                              hipStream_t stream) {
  const float* X  = (const float*)d_in[0];  // [8192][1024]
  const float* W1 = (const float*)d_in[1];  // [1024][4096]
  const float* b1 = (const float*)d_in[2];  // [4096]
  const float* W2 = (const float*)d_in[3];  // [4096][1024]
  const float* b2 = (const float*)d_in[4];  // [1024]
  float* out = (float*)d_out;               // [8192][1024] f32

  const int M = 8192, H = 1024, I = 4096;
  const size_t MB = 1024 * 1024;

  char* ws = (char*)d_ws;
  unsigned short* W1t = (unsigned short*)ws;            // [I][H] bf16, 8 MB
  unsigned short* W2t = (unsigned short*)(ws + 8 * MB); // [H][I] bf16, 8 MB

  transpose_cvt<<<dim3(I / 32, H / 32), dim3(32, 8), 0, stream>>>(W1, W1t, H, I);
  transpose_cvt<<<dim3(H / 32, I / 32), dim3(32, 8), 0, stream>>>(W2, W2t, I, H);

  if (ws_size >= 80 * MB) {
    // Fast path: k-half 8-phase 256-row GEMMs. Xbf parked in d_out tail
    // (fully consumed by L1 before the single L2 dispatch writes d_out).
    unsigned short* Xbf = (unsigned short*)((char*)d_out + 16 * MB);
    unsigned short* Hbf = (unsigned short*)(ws + 16 * MB);   // [M][I] bf16
    int n4 = (M * H) / 4;
    cvt_f32_bf16<<<(n4 + 255) / 256, 256, 0, stream>>>(X, Xbf, n4);
    // L1: Hbf = relu(X*W1+b1). BM=256,BN=256, grid 16x32=512, LDS 128 KiB.
    gemm_kh<256, 1><<<512, 512, 131072, stream>>>(
        Xbf, H, W1t, H, b1, Hbf, I, H, I / 256);
    // L2: out = Hbf*W2+b2. BM=256,BN=128, grid 8x32=256, LDS 96 KiB.
    gemm_kh<128, 0><<<256, 512, 98304, stream>>>(
        Hbf, I, W2t, I, b2, out, H, I, H / 128);
    return;
  }

  // Fallback: round-2 adaptive chunked path (verified).
  int Ic, useXbf;
  unsigned short* Xbf = nullptr;
  unsigned short* Hc;
  if (ws_size >= 64 * MB) {
    Ic = 2048; useXbf = 1;
    Xbf = (unsigned short*)(ws + 16 * MB);
    Hc  = (unsigned short*)(ws + 32 * MB);
  } else if (ws_size >= 48 * MB) {
    Ic = 1024; useXbf = 1;
    Xbf = (unsigned short*)(ws + 16 * MB);
    Hc  = (unsigned short*)(ws + 32 * MB);
  } else if (ws_size >= 32 * MB) {
    Ic = 1024; useXbf = 0;
    Hc  = (unsigned short*)(ws + 16 * MB);
  } else if (ws_size >= 24 * MB) {
    Ic = 512;  useXbf = 0;
    Hc  = (unsigned short*)(ws + 16 * MB);
  } else if (ws_size >= 20 * MB) {
    Ic = 256;  useXbf = 0;
    Hc  = (unsigned short*)(ws + 16 * MB);
  } else {
    Ic = 128;  useXbf = 0;
    Hc  = (unsigned short*)(ws + 16 * MB);
  }

  if (useXbf) {
    int n4 = (M * H) / 4;
    cvt_f32_bf16<<<(n4 + 255) / 256, 256, 0, stream>>>(X, Xbf, n4);
  }

  const int nch = I / Ic;
  for (int c = 0; c < nch; ++c) {
    const int i0 = c * Ic;
    if (useXbf)
      gemm_bf16<0, 1><<<dim3(Ic / 128, M / 128), 256, 0, stream>>>(
          Xbf, H, W1t + (size_t)i0 * H, H, b1 + i0, Hc, Ic, H, 0);
    else
      gemm_bf16<1, 1><<<dim3(Ic / 128, M / 128), 256, 0, stream>>>(
          X, H, W1t + (size_t)i0 * H, H, b1 + i0, Hc, Ic, H, 0);
    gemm_bf16<0, 0><<<dim3(H / 128, M / 128), 256, 0, stream>>>(
        Hc, Ic, W2t + i0, I, b2, out, H, Ic, c > 0);
  }
}